// Round 1
// baseline (624.503 us; speedup 1.0000x reference)
//
#include <hip/hip_runtime.h>
#include <hip/hip_bf16.h>
#include <math.h>

#define NN 8192
#define FF 64
#define HH 128
#define RR 3
#define DEG 32
#define KK 32
#define EE (NN*DEG)
#define DD 131            // 2F+3
#define TEMP 0.3f
#define NEG_SLOPE 0.2f
#define EPS_LN 1e-5f
#define W_THRESH 1e-6f

// ws layout (floats): [0]=contagion_sum [1..3]=regime_probs [4]=amp [8..71]=colsum
// [128 .. 128+E) = edge scores

// ---------------- Kernel A: column sums of x + contagion level ----------------
__global__ __launch_bounds__(256) void stats_kernel(
    const float* __restrict__ x, const float* __restrict__ Wc1,
    const float* __restrict__ bc1, const float* __restrict__ Wc2,
    const float* __restrict__ bc2, float* __restrict__ hdr)
{
    __shared__ float xs[64 * 65];      // 64 nodes x 64 feats, pad 65
    __shared__ float wl[64 * 128];     // Wc1
    __shared__ float cs[4][64];
    int t = threadIdx.x;
    int n0 = blockIdx.x * 64;

    for (int i = 0; i < 16; i++) {
        int flat = t + i * 256;        // 4096 floats
        int r = flat >> 6, c = flat & 63;
        xs[r * 65 + c] = x[(n0 + r) * 64 + c];
    }
    for (int i = 0; i < 32; i++) {
        int flat = t + i * 256;        // 8192 floats
        wl[flat] = Wc1[flat];
    }
    __syncthreads();

    // column partial sums
    {
        int col = t & 63, g = t >> 6;
        float ps = 0.f;
        for (int r = g * 16; r < g * 16 + 16; r++) ps += xs[r * 65 + col];
        cs[g][col] = ps;
    }
    __syncthreads();
    if (t < 64) {
        float v = cs[0][t] + cs[1][t] + cs[2][t] + cs[3][t];
        atomicAdd(&hdr[8 + t], v);
    }

    // contagion: 4 threads per node, thread q handles h = q, q+4, ..., q+124
    int r = t >> 2, q = t & 3;
    float accl = 0.f;
    for (int hh = 0; hh < 32; hh++) {
        int h = hh * 4 + q;
        float s = bc1[h];
        for (int i = 0; i < 64; i++) s += xs[r * 65 + i] * wl[i * 128 + h];
        accl += fmaxf(s, 0.f) * Wc2[h];
    }
    accl += __shfl_xor(accl, 1);
    accl += __shfl_xor(accl, 2);
    if (q == 0) {
        float lvl = 1.f / (1.f + expf(-(accl + bc2[0])));
        atomicAdd(&hdr[0], lvl);
    }
}

// ---------------- Kernel B: regime probs + amp ----------------
__global__ __launch_bounds__(128) void regime_kernel(
    const float* __restrict__ Wr1, const float* __restrict__ br1,
    const float* __restrict__ Wr2, const float* __restrict__ br2,
    float* __restrict__ hdr)
{
    __shared__ float gsl[64];
    __shared__ float t1[128];
    int t = threadIdx.x;
    if (t < 64) gsl[t] = hdr[8 + t] * (1.f / (float)NN);
    __syncthreads();
    float a = br1[t];
    for (int i = 0; i < 64; i++) a += gsl[i] * Wr1[i * 128 + t];
    t1[t] = fmaxf(a, 0.f);
    __syncthreads();
    if (t < 3) {
        float v = br2[t];
        for (int h = 0; h < 128; h++) v += t1[h] * Wr2[h * 3 + t];
        gsl[32 + t] = v;
    }
    __syncthreads();
    if (t == 0) {
        float v0 = gsl[32], v1 = gsl[33], v2 = gsl[34];
        float m = fmaxf(v0, fmaxf(v1, v2));
        float e0 = expf(v0 - m), e1 = expf(v1 - m), e2 = expf(v2 - m);
        float inv = 1.f / (e0 + e1 + e2);
        hdr[1] = e0 * inv; hdr[2] = e1 * inv; hdr[3] = e2 * inv;
        hdr[4] = 1.f + 0.5f * (hdr[0] * (1.f / (float)NN));
    }
}

// ---------------- Kernel C: per-edge scores (the big one) ----------------
// block = 256 threads, tile = 64 edges (2 source nodes). 4096 blocks.
#define EI_STRIDE 140
__global__ __launch_bounds__(256) void edge_score_kernel(
    const float* __restrict__ x, const int* __restrict__ tgt_idx,
    const float* __restrict__ edge_attr,
    const float* __restrict__ Ws1, const float* __restrict__ bs1,
    const float* __restrict__ ln_g, const float* __restrict__ ln_b,
    const float* __restrict__ Ws2, const float* __restrict__ bs2,
    const float* __restrict__ Wp, const float* __restrict__ bp,
    const float* __restrict__ Wg1, const float* __restrict__ bg1,
    const float* __restrict__ Wg2, const float* __restrict__ bg2,
    const float* __restrict__ hdr, float* __restrict__ scores)
{
    __shared__ float EI[64 * EI_STRIDE];   // edge_input, later reused for edge_hidden
    __shared__ float WPan[8 * 128];        // weight k-panel
    __shared__ float rawS[64];
    __shared__ float gateC[64];

    int t = threadIdx.x;
    int e0 = blockIdx.x * 64;

    // ---- stage edge_input (zero-pad cols 131..139) ----
    {
        int r = t >> 2, q = t & 3;
        int e = e0 + r;
        int src = e >> 5;                  // e / DEG
        int tg = tgt_idx[e];
        for (int ii = q; ii < EI_STRIDE; ii += 4) {
            float v;
            if (ii < 64) v = x[src * 64 + ii];
            else if (ii < 128) v = x[tg * 64 + (ii - 64)];
            else if (ii < 131) v = edge_attr[e * 3 + (ii - 128)];
            else v = 0.f;
            EI[r * EI_STRIDE + ii] = v;
        }
    }

    int tcol = t & 7, trow = t >> 3;       // cols: tcol*4 + j*32 + c ; rows: 2*trow, 2*trow+1
    const float* EIr0 = &EI[(2 * trow) * EI_STRIDE];
    const float* EIr1 = EIr0 + EI_STRIDE;

    float acc0[16], acc1[16];

    // ================= GEMM 1: h = EI @ Ws1 =================
    #pragma unroll
    for (int j = 0; j < 16; j++) { acc0[j] = 0.f; acc1[j] = 0.f; }
    for (int k0 = 0; k0 < 136; k0 += 8) {
        __syncthreads();
        {
            int flat = t * 4;
            int pr = flat >> 7, pc = flat & 127;
            int krow = k0 + pr;
            float4 w;
            if (krow < 131) w = *(const float4*)&Ws1[krow * 128 + pc];
            else w = make_float4(0.f, 0.f, 0.f, 0.f);
            *(float4*)&WPan[pr * 128 + pc] = w;
        }
        __syncthreads();
        #pragma unroll
        for (int kk = 0; kk < 8; kk++) {
            float a0 = EIr0[k0 + kk];
            float a1 = EIr1[k0 + kk];
            const float* wrow = &WPan[kk * 128];
            #pragma unroll
            for (int j = 0; j < 4; j++) {
                float4 w = *(const float4*)&wrow[tcol * 4 + j * 32];
                acc0[j*4+0] += a0 * w.x; acc0[j*4+1] += a0 * w.y;
                acc0[j*4+2] += a0 * w.z; acc0[j*4+3] += a0 * w.w;
                acc1[j*4+0] += a1 * w.x; acc1[j*4+1] += a1 * w.y;
                acc1[j*4+2] += a1 * w.z; acc1[j*4+3] += a1 * w.w;
            }
        }
    }

    // ---- +bias, LayerNorm (over 128 cols = 8 lanes x 16), LeakyReLU, dot Ws2 ----
    {
        float s0 = 0.f, ss0 = 0.f, s1 = 0.f, ss1 = 0.f;
        #pragma unroll
        for (int j = 0; j < 16; j++) {
            int col = tcol * 4 + (j >> 2) * 32 + (j & 3);
            float b = bs1[col];
            acc0[j] += b; acc1[j] += b;
            s0 += acc0[j]; ss0 += acc0[j] * acc0[j];
            s1 += acc1[j]; ss1 += acc1[j] * acc1[j];
        }
        #pragma unroll
        for (int m = 1; m < 8; m <<= 1) {
            s0 += __shfl_xor(s0, m);  ss0 += __shfl_xor(ss0, m);
            s1 += __shfl_xor(s1, m);  ss1 += __shfl_xor(ss1, m);
        }
        float mu0 = s0 * (1.f / 128.f), mu1 = s1 * (1.f / 128.f);
        float var0 = ss0 * (1.f / 128.f) - mu0 * mu0;
        float var1 = ss1 * (1.f / 128.f) - mu1 * mu1;
        float inv0 = 1.f / sqrtf(var0 + EPS_LN);
        float inv1 = 1.f / sqrtf(var1 + EPS_LN);
        float d0 = 0.f, d1 = 0.f;
        #pragma unroll
        for (int j = 0; j < 16; j++) {
            int col = tcol * 4 + (j >> 2) * 32 + (j & 3);
            float g = ln_g[col], bb = ln_b[col], w2 = Ws2[col];
            float y0 = (acc0[j] - mu0) * inv0 * g + bb;
            float y1 = (acc1[j] - mu1) * inv1 * g + bb;
            y0 = (y0 >= 0.f) ? y0 : NEG_SLOPE * y0;
            y1 = (y1 >= 0.f) ? y1 : NEG_SLOPE * y1;
            d0 += y0 * w2; d1 += y1 * w2;
        }
        #pragma unroll
        for (int m = 1; m < 8; m <<= 1) {
            d0 += __shfl_xor(d0, m); d1 += __shfl_xor(d1, m);
        }
        if (tcol == 0) {
            rawS[2 * trow]     = d0 + bs2[0];
            rawS[2 * trow + 1] = d1 + bs2[0];
        }
    }

    // ================= GEMM 2: eh = relu(EI @ Wp + bp) =================
    #pragma unroll
    for (int j = 0; j < 16; j++) { acc0[j] = 0.f; acc1[j] = 0.f; }
    for (int k0 = 0; k0 < 136; k0 += 8) {
        __syncthreads();
        {
            int flat = t * 4;
            int pr = flat >> 7, pc = flat & 127;
            int krow = k0 + pr;
            float4 w;
            if (krow < 131) w = *(const float4*)&Wp[krow * 128 + pc];
            else w = make_float4(0.f, 0.f, 0.f, 0.f);
            *(float4*)&WPan[pr * 128 + pc] = w;
        }
        __syncthreads();
        #pragma unroll
        for (int kk = 0; kk < 8; kk++) {
            float a0 = EIr0[k0 + kk];
            float a1 = EIr1[k0 + kk];
            const float* wrow = &WPan[kk * 128];
            #pragma unroll
            for (int j = 0; j < 4; j++) {
                float4 w = *(const float4*)&wrow[tcol * 4 + j * 32];
                acc0[j*4+0] += a0 * w.x; acc0[j*4+1] += a0 * w.y;
                acc0[j*4+2] += a0 * w.z; acc0[j*4+3] += a0 * w.w;
                acc1[j*4+0] += a1 * w.x; acc1[j*4+1] += a1 * w.y;
                acc1[j*4+2] += a1 * w.z; acc1[j*4+3] += a1 * w.w;
            }
        }
    }
    __syncthreads();                       // all GEMM2 EI reads done
    #pragma unroll
    for (int j = 0; j < 16; j++) {
        int col = tcol * 4 + (j >> 2) * 32 + (j & 3);
        float b = bp[col];
        EI[(2 * trow) * EI_STRIDE + col]     = fmaxf(acc0[j] + b, 0.f);
        EI[(2 * trow + 1) * EI_STRIDE + col] = fmaxf(acc1[j] + b, 0.f);
    }
    __syncthreads();

    // ================= Gating: 3 regimes, eh(64x128) @ Wg1[r](128x64) =================
    {
        float rp0 = hdr[1], rp1 = hdr[2], rp2 = hdr[3];
        float regp[3] = { rp0, rp1, rp2 };
        int grow = t >> 2, gq = t & 3;     // m = gq*4 + j*16 + c
        const float* ehr = &EI[grow * EI_STRIDE];
        float gc = 0.f;
        for (int r = 0; r < 3; r++) {
            float acc[16];
            #pragma unroll
            for (int j = 0; j < 16; j++) acc[j] = 0.f;
            for (int k0 = 0; k0 < 128; k0 += 8) {
                __syncthreads();
                {
                    int flat = t * 2;      // 512 floats
                    int pr = flat >> 6, pc = flat & 63;
                    *(float2*)&WPan[pr * 64 + pc] =
                        *(const float2*)&Wg1[((r * 128) + (k0 + pr)) * 64 + pc];
                }
                __syncthreads();
                #pragma unroll
                for (int kk = 0; kk < 8; kk++) {
                    float a = ehr[k0 + kk];
                    const float* wrow = &WPan[kk * 64];
                    #pragma unroll
                    for (int j = 0; j < 4; j++) {
                        float4 w = *(const float4*)&wrow[gq * 4 + j * 16];
                        acc[j*4+0] += a * w.x; acc[j*4+1] += a * w.y;
                        acc[j*4+2] += a * w.z; acc[j*4+3] += a * w.w;
                    }
                }
            }
            float p = 0.f;
            #pragma unroll
            for (int j = 0; j < 16; j++) {
                int m = gq * 4 + (j >> 2) * 16 + (j & 3);
                float g1 = fmaxf(acc[j] + bg1[r * 64 + m], 0.f);
                p += g1 * Wg2[r * 64 + m];
            }
            p += __shfl_xor(p, 1);
            p += __shfl_xor(p, 2);
            float gate = 1.f / (1.f + expf(-(p + bg2[r])));
            gc += gate * regp[r];
        }
        if (gq == 0) gateC[grow] = gc;
    }
    __syncthreads();

    if (t < 64) {
        float amp = hdr[4];
        scores[e0 + t] = rawS[t] * gateC[t] * amp;
    }
}

// ---------------- Kernel D: per-row dedup + softmax + stable top-k ----------------
__global__ __launch_bounds__(64) void finalize_kernel(
    const int* __restrict__ tgt_idx, const float* __restrict__ scores,
    float* __restrict__ out_w, float* __restrict__ out_i)
{
    __shared__ int   tl[32];
    __shared__ float pl[32];
    int j = threadIdx.x;
    int row = blockIdx.x;
    bool lane_active = (j < 32);
    int   tg = 0;
    float s  = -INFINITY;
    if (lane_active) {
        tg = tgt_idx[row * 32 + j];
        s  = scores[row * 32 + j];
        tl[j] = tg;
    }
    __syncthreads();

    bool alive = false;
    if (lane_active) {
        alive = true;
        for (int j2 = j + 1; j2 < 32; j2++)
            if (tl[j2] == tg) { alive = false; break; }
    }
    float z = (lane_active && alive) ? s * (1.f / TEMP) : -INFINITY;
    float m = z;
    #pragma unroll
    for (int mm = 1; mm < 64; mm <<= 1) m = fmaxf(m, __shfl_xor(m, mm));
    float p = (lane_active && alive) ? expf(z - m) : 0.f;
    float sum = p;
    #pragma unroll
    for (int mm = 1; mm < 64; mm <<= 1) sum += __shfl_xor(sum, mm);
    p = p / sum;
    if (lane_active) pl[j] = alive ? p : -1.f;   // -1 marks dead (dup overwritten)
    __syncthreads();

    int rank = 0, dcount = 0;
    for (int j2 = 0; j2 < 32; j2++) {
        float pj = pl[j2];
        if (pj >= 0.f) {
            dcount++;
            if (lane_active && alive) {
                if (pj > p || (pj == p && tl[j2] < tg)) rank++;
            }
        }
    }
    if (lane_active && alive) {
        out_w[row * 32 + rank] = (p > W_THRESH) ? p : 0.f;
        out_i[row * 32 + rank] = (float)tg;
    }
    if (j == 0) {
        int c = 0;
        for (int slot = dcount; slot < 32; slot++) {
            for (;;) {
                bool found = false;
                for (int q = 0; q < 32; q++) if (tl[q] == c) { found = true; break; }
                if (!found) break;
                c++;
            }
            out_w[row * 32 + slot] = 0.f;
            out_i[row * 32 + slot] = (float)c;
            c++;
        }
    }
}

extern "C" void kernel_launch(void* const* d_in, const int* in_sizes, int n_in,
                              void* d_out, int out_size, void* d_ws, size_t ws_size,
                              hipStream_t stream)
{
    const float* x          = (const float*)d_in[0];
    const int*   edge_index = (const int*)  d_in[1];
    const float* edge_attr  = (const float*)d_in[2];
    const float* Ws1 = (const float*)d_in[3];
    const float* bs1 = (const float*)d_in[4];
    const float* ln_g = (const float*)d_in[5];
    const float* ln_b = (const float*)d_in[6];
    const float* Ws2 = (const float*)d_in[7];
    const float* bs2 = (const float*)d_in[8];
    const float* Wp  = (const float*)d_in[9];
    const float* bp  = (const float*)d_in[10];
    const float* Wr1 = (const float*)d_in[11];
    const float* br1 = (const float*)d_in[12];
    const float* Wr2 = (const float*)d_in[13];
    const float* br2 = (const float*)d_in[14];
    const float* Wg1 = (const float*)d_in[15];
    const float* bg1 = (const float*)d_in[16];
    const float* Wg2 = (const float*)d_in[17];
    const float* bg2 = (const float*)d_in[18];
    const float* Wc1 = (const float*)d_in[19];
    const float* bc1 = (const float*)d_in[20];
    const float* bcw2 = (const float*)d_in[21];   // Wc2
    const float* bc2 = (const float*)d_in[22];

    float* hdr    = (float*)d_ws;
    float* scores = hdr + 128;
    const int* tgt = edge_index + EE;   // row 1 of edge_index

    hipMemsetAsync(d_ws, 0, 512, stream);
    stats_kernel<<<128, 256, 0, stream>>>(x, Wc1, bc1, bcw2, bc2, hdr);
    regime_kernel<<<1, 128, 0, stream>>>(Wr1, br1, Wr2, br2, hdr);
    edge_score_kernel<<<EE / 64, 256, 0, stream>>>(
        x, tgt, edge_attr, Ws1, bs1, ln_g, ln_b, Ws2, bs2, Wp, bp,
        Wg1, bg1, Wg2, bg2, hdr, scores);
    finalize_kernel<<<NN, 64, 0, stream>>>(
        tgt, scores, (float*)d_out, (float*)d_out + NN * KK);
}